// Round 12
// baseline (159.257 us; speedup 1.0000x reference)
//
#include <hip/hip_runtime.h>
#include <hip/hip_bf16.h>

// B=4, L=1024, D=1024, H=16, DH=64. Inputs fp32 (proven R0-R4). Output fp32.
// Q pre-scaled by 0.125*log2(e) at proj; pmask pre-scaled by log2(e) at conv.
// Fixed-max exp2 softmax (m=12). R12 = R11 + attn K/V double-buffer:
//   one barrier per kt-iter; gll for kt+1 issued right after the barrier and
//   hidden behind kt's compute (72 MFMA + softmax VALU). PsF single + WAR
//   fence (LDS 80KB -> 2 blocks/CU, grid-capped anyway).
// ws elem offsets (bf16): Q[0,4M) K[4M,8M) V^T[8M,12M) seq@12582912
//   Wq@16777216 Wk@17825792 Wv@18874368 bq@20971520 bk@20972544 bv@20973568 pm@20974592

#define LL 1024

typedef __attribute__((ext_vector_type(8))) short short8;
typedef __attribute__((ext_vector_type(4))) float floatx4;

__device__ __forceinline__ float bf2f(unsigned short u) {
    return __uint_as_float(((unsigned int)u) << 16);
}
__device__ __forceinline__ unsigned short f2bf(float f) {
    unsigned int x = __float_as_uint(f);
    unsigned int r = x + 0x7fffu + ((x >> 16) & 1u);
    return (unsigned short)(r >> 16);
}

#if __has_builtin(__builtin_amdgcn_global_load_lds)
#define HAVE_GLL 1
typedef __attribute__((address_space(1))) unsigned int as1_u32;
typedef __attribute__((address_space(3))) unsigned int as3_u32;
__device__ __forceinline__ void gll16(const void* g, void* l) {
    __builtin_amdgcn_global_load_lds((const as1_u32*)g, (as3_u32*)l, 16, 0, 0);
}
#endif

#if __has_builtin(__builtin_amdgcn_exp2f)
#define EXP2F(x) __builtin_amdgcn_exp2f(x)
#else
#define EXP2F(x) exp2f(x)
#endif

// ---- fp32 -> clean bf16 conversion, vectorized x8 ----
__global__ __launch_bounds__(256) void conv_in(
    const float* __restrict__ seq, const float* __restrict__ wq,
    const float* __restrict__ wk,  const float* __restrict__ wv,
    const float* __restrict__ bq,  const float* __restrict__ bk,
    const float* __restrict__ bv,  const float* __restrict__ pm,
    unsigned short* __restrict__ ws)
{
    unsigned int t = blockIdx.x * 256u + threadIdx.x;   // grid 3588 -> 918,400 x8
    if (t >= 918400u) return;
    unsigned int e = t * 8u;
    const float* src; unsigned int idx; unsigned short* dst; float scale = 1.0f;
    if (e < 4194304u)      { src = seq; idx = e;            dst = ws + 12582912u; }
    else if (e < 5242880u) { src = wq;  idx = e - 4194304u; dst = ws + 16777216u; }
    else if (e < 6291456u) { src = wk;  idx = e - 5242880u; dst = ws + 17825792u; }
    else if (e < 7340032u) { src = wv;  idx = e - 6291456u; dst = ws + 18874368u; }
    else if (e < 7341056u) { src = bq;  idx = e - 7340032u; dst = ws + 20971520u; }
    else if (e < 7342080u) { src = bk;  idx = e - 7341056u; dst = ws + 20972544u; }
    else if (e < 7343104u) { src = bv;  idx = e - 7342080u; dst = ws + 20973568u; }
    else { src = pm; idx = e - 7343104u; dst = ws + 20974592u; scale = 1.4426950f; }
    float4 a = *(const float4*)(src + idx);
    float4 c = *(const float4*)(src + idx + 4);
    uint4 st;
    st.x = (unsigned)f2bf(a.x * scale) | ((unsigned)f2bf(a.y * scale) << 16);
    st.y = (unsigned)f2bf(a.z * scale) | ((unsigned)f2bf(a.w * scale) << 16);
    st.z = (unsigned)f2bf(c.x * scale) | ((unsigned)f2bf(c.y * scale) << 16);
    st.w = (unsigned)f2bf(c.z * scale) | ((unsigned)f2bf(c.w * scale) << 16);
    *(uint4*)(dst + idx) = st;
}

// ---------------- QKV projection (R7, unchanged: 49 us, 0 conflicts) ---------------
__global__ __launch_bounds__(256) void qkv_proj(
    const unsigned short* __restrict__ X,
    const unsigned short* __restrict__ Wq, const unsigned short* __restrict__ bq,
    const unsigned short* __restrict__ Wk, const unsigned short* __restrict__ bk,
    const unsigned short* __restrict__ Wv, const unsigned short* __restrict__ bv,
    unsigned short* __restrict__ dst_base)
{
    const int z = blockIdx.z;
    const unsigned short* W    = (z == 0) ? Wq : ((z == 1) ? Wk : Wv);
    const unsigned short* bias = (z == 0) ? bq : ((z == 1) ? bk : bv);
    const float osc = (z == 0) ? 0.18033688f : 1.0f;   // 0.125 * log2(e)
    unsigned short* dst = dst_base + (size_t)z * (4096u * 1024u);

    __shared__ __align__(16) unsigned short AsF[8192];   // [128 rows][64], col-swizzled
    __shared__ __align__(16) unsigned short BsF[8192];

    const int tid  = threadIdx.x;
    const int lane = tid & 63;
    const int wave = tid >> 6;
    const int quad = lane >> 4, r16 = lane & 15;
    const int wr = wave >> 1, wc = wave & 1;
    const int m0 = blockIdx.x * 128;
    const int n0 = blockIdx.y * 128;

    const int st_r3  = lane >> 3;
    const int st_col = ((lane & 7) ^ st_r3) << 3;

    floatx4 acc[4][4];
#pragma unroll
    for (int i = 0; i < 4; ++i)
#pragma unroll
        for (int j = 0; j < 4; ++j)
#pragma unroll
            for (int r = 0; r < 4; ++r) acc[i][j][r] = 0.f;

    for (int k0 = 0; k0 < 1024; k0 += 64) {
        __syncthreads();
#ifdef HAVE_GLL
#pragma unroll
        for (int c2 = 0; c2 < 4; ++c2) {
            int seg = wave * 4 + c2;
            int row = seg * 8 + st_r3;
            gll16(X + (size_t)(m0 + row) * 1024 + k0 + st_col, &AsF[seg * 512]);
            gll16(W + (size_t)(n0 + row) * 1024 + k0 + st_col, &BsF[seg * 512]);
        }
#else
#pragma unroll
        for (int c2 = 0; c2 < 4; ++c2) {
            int seg = wave * 4 + c2;
            int row = seg * 8 + st_r3;
            *(uint4*)&AsF[seg * 512 + lane * 8] = *(const uint4*)(X + (size_t)(m0 + row) * 1024 + k0 + st_col);
            *(uint4*)&BsF[seg * 512 + lane * 8] = *(const uint4*)(W + (size_t)(n0 + row) * 1024 + k0 + st_col);
        }
#endif
        __syncthreads();

#pragma unroll
        for (int kk = 0; kk < 2; ++kk) {
            const int csw = ((kk * 4 + quad) ^ (r16 & 7)) << 3;
            short8 a[4], b[4];
#pragma unroll
            for (int i = 0; i < 4; ++i)
                a[i] = *(const short8*)&AsF[(wr * 64 + i * 16 + r16) * 64 + csw];
#pragma unroll
            for (int j = 0; j < 4; ++j)
                b[j] = *(const short8*)&BsF[(wc * 64 + j * 16 + r16) * 64 + csw];
#pragma unroll
            for (int i = 0; i < 4; ++i)
#pragma unroll
                for (int j = 0; j < 4; ++j)
                    acc[i][j] = __builtin_amdgcn_mfma_f32_16x16x32_bf16(a[i], b[j], acc[i][j], 0, 0, 0);
        }
    }

#pragma unroll
    for (int j = 0; j < 4; ++j) {
        int n = n0 + wc * 64 + j * 16 + r16;
        float bvf = bf2f(bias[n]);
        int h = n >> 6, d = n & 63;
#pragma unroll
        for (int i = 0; i < 4; ++i) {
            int m_base = m0 + wr * 64 + i * 16 + quad * 4;
            int b = m_base >> 10, l0 = m_base & 1023;
            if (z == 2) {
                ushort4 st;
                st.x = f2bf(acc[i][j][0] + bvf); st.y = f2bf(acc[i][j][1] + bvf);
                st.z = f2bf(acc[i][j][2] + bvf); st.w = f2bf(acc[i][j][3] + bvf);
                *(ushort4*)&dst[(((size_t)(b * 16 + h)) * 64 + d) * 1024 + l0] = st;
            } else {
#pragma unroll
                for (int r = 0; r < 4; ++r)
                    dst[(((size_t)(b * 16 + h)) * 1024 + (l0 + r)) * 64 + d] =
                        f2bf((acc[i][j][r] + bvf) * osc);
            }
        }
    }
}

// ---- K/V tile staging (fragment-swizzled), used for prologue + in-loop prefetch ----
__device__ __forceinline__ void stage_kv(
    const unsigned short* __restrict__ Kg, const unsigned short* __restrict__ Vg,
    int kt, unsigned short* __restrict__ KsBuf, unsigned short* __restrict__ VsBuf,
    int lane, int wave, int kst_r3, int kst_col, int vst_r)
{
#ifdef HAVE_GLL
#pragma unroll
    for (int c2 = 0; c2 < 4; ++c2) {
        int seg = wave * 4 + c2;
        int krow = seg * 8 + kst_r3;
        gll16(Kg + (size_t)(kt * 128 + krow) * 64 + kst_col, KsBuf + seg * 512);
        int vrow = seg * 4 + vst_r;
        int vcol = (((lane & 15) ^ (vrow & 7))) << 3;
        gll16(Vg + (size_t)vrow * 1024 + kt * 128 + vcol, VsBuf + seg * 512);
    }
#else
#pragma unroll
    for (int c2 = 0; c2 < 4; ++c2) {
        int seg = wave * 4 + c2;
        int krow = seg * 8 + kst_r3;
        *(uint4*)(KsBuf + seg * 512 + lane * 8) =
            *(const uint4*)(Kg + (size_t)(kt * 128 + krow) * 64 + kst_col);
        int vrow = seg * 4 + vst_r;
        int vcol = (((lane & 15) ^ (vrow & 7))) << 3;
        *(uint4*)(VsBuf + seg * 512 + lane * 8) =
            *(const uint4*)(Vg + (size_t)vrow * 1024 + kt * 128 + vcol);
    }
#endif
}

// ---------------- fused flash attention: K/V dbuf, 1 barrier/iter ------------------
__global__ __launch_bounds__(256) void attn(
    const unsigned short* __restrict__ Qw,     // (B,H,L,DH), pre-scaled by 0.125*log2e
    const unsigned short* __restrict__ Kw,     // (B,H,L,DH)
    const unsigned short* __restrict__ Vt_g,   // (B*H, DH, L)
    const unsigned short* __restrict__ pmask,  // (B,L), pre-scaled by log2e
    float* __restrict__ out)                   // (B,L,D) fp32
{
    __shared__ __align__(16) unsigned short KsF[2][8192];   // dbuf [128 key][64], swizzled
    __shared__ __align__(16) unsigned short VsF[2][8192];   // dbuf [64 dh][128], swizzled
    __shared__ __align__(16) unsigned short PsF[4][2048];   // per-wave, frag order

    const int tid  = threadIdx.x;
    const int lane = tid & 63;
    const int wave = tid >> 6;
    const int quad = lane >> 4, r16 = lane & 15;

    // XCD-aware map (R11): bh in low 6 bits; complementary qi in high bits.
    const int bid  = blockIdx.x;
    const int half = bid >> 8, idx = bid & 255;
    const int bh   = idx & 63;
    const int qb   = idx >> 6;
    const int qi   = half ? (7 - qb) : qb;
    const int b    = bh >> 4, h = bh & 15;
    const int q0   = qi << 7;

    const size_t base = (size_t)bh * (1024 * 64);
    const unsigned short* Qg = Qw + base;
    const unsigned short* Kg = Kw + base;
    const unsigned short* Vg = Vt_g + base;

    const int kst_r3  = lane >> 3;
    const int kst_col = ((lane & 7) ^ kst_r3) << 3;
    const int vst_r   = lane >> 4;

    short8 aq[2][2];
#pragma unroll
    for (int f = 0; f < 2; ++f) {
        int qrow = q0 + f * 64 + wave * 16 + r16;
        aq[f][0] = *(const short8*)(Qg + (size_t)qrow * 64 + quad * 8);
        aq[f][1] = *(const short8*)(Qg + (size_t)qrow * 64 + 32 + quad * 8);
    }

    short8 ones;
#pragma unroll
    for (int i = 0; i < 8; ++i) ones[i] = (short)0x3f80;   // 1.0 bf16

    floatx4 ol[2];     // l accumulators via MFMA (P * ones, C-layout)
    floatx4 o[2][4];
#pragma unroll
    for (int f = 0; f < 2; ++f)
#pragma unroll
        for (int r = 0; r < 4; ++r) ol[f][r] = 0.f;
#pragma unroll
    for (int f = 0; f < 2; ++f)
#pragma unroll
        for (int j = 0; j < 4; ++j)
#pragma unroll
            for (int r = 0; r < 4; ++r) o[f][j][r] = 0.f;

    // prologue: stage tile 0 into buffer 0
    stage_kv(Kg, Vg, 0, KsF[0], VsF[0], lane, wave, kst_r3, kst_col, vst_r);

    for (int kt = 0; kt <= qi; ++kt) {
        // pmask for kt: independent load, overlaps the barrier drain
        float pm2[8];
#pragma unroll
        for (int j = 0; j < 8; ++j)
            pm2[j] = bf2f(pmask[b * LL + kt * 128 + j * 16 + r16]) - 12.0f;  // fixed max

        // ONE barrier: drains this wave's gll for kt (vmcnt0) and all waves'
        // ds_reads of the opposite buffer from iter kt-1 (lgkmcnt0) -> safe to
        // overwrite that buffer with kt+1's prefetch.
        __syncthreads();
        if (kt < qi)
            stage_kv(Kg, Vg, kt + 1, KsF[(kt + 1) & 1], VsF[(kt + 1) & 1],
                     lane, wave, kst_r3, kst_col, vst_r);

        const unsigned short* Ks = KsF[kt & 1];
        const unsigned short* Vs = VsF[kt & 1];

#pragma unroll
        for (int f = 0; f < 2; ++f) {
            floatx4 s[8];
#pragma unroll
            for (int j = 0; j < 8; ++j)
#pragma unroll
                for (int r = 0; r < 4; ++r) s[j][r] = 0.f;
#pragma unroll
            for (int j = 0; j < 8; ++j) {
                short8 bk0 = *(const short8*)&Ks[(j * 16 + r16) * 64 + (((0 * 4 + quad) ^ (r16 & 7)) << 3)];
                s[j] = __builtin_amdgcn_mfma_f32_16x16x32_bf16(aq[f][0], bk0, s[j], 0, 0, 0);
                short8 bk1 = *(const short8*)&Ks[(j * 16 + r16) * 64 + (((1 * 4 + quad) ^ (r16 & 7)) << 3)];
                s[j] = __builtin_amdgcn_mfma_f32_16x16x32_bf16(aq[f][1], bk1, s[j], 0, 0, 0);
            }

            if (kt == qi) {   // diagonal tile: causal mask (wave-uniform branch)
                const int my_q = q0 + f * 64 + wave * 16 + quad * 4;
#pragma unroll
                for (int j = 0; j < 8; ++j) {
                    int key = kt * 128 + j * 16 + r16;
#pragma unroll
                    for (int r = 0; r < 4; ++r)
                        if (key > my_q + r) s[j][r] -= 1.0e9f;
                }
            }

            // fixed-max exp2 softmax; P -> PsF (single buffer: WAR fence first)
            asm volatile("s_waitcnt lgkmcnt(0)" ::: "memory");  // WAR on PsF[wave]
#pragma unroll
            for (int j = 0; j < 8; ++j) {
                int key = j * 16 + r16;
                int ab = ((key >> 5) << 9) + (((key >> 3) & 3) << 7) + (key & 7) + (quad << 5);
#pragma unroll
                for (int r = 0; r < 4; ++r) {
                    float p = EXP2F(s[j][r] + pm2[j]);
                    PsF[wave][ab + (r << 3)] = (unsigned short)(__float_as_uint(p) >> 16);
                }
            }
            asm volatile("s_waitcnt lgkmcnt(0)" ::: "memory");  // RAW on PsF[wave]

#pragma unroll
            for (int kk4 = 0; kk4 < 4; ++kk4) {
                short8 ap = *(const short8*)&PsF[wave][kk4 * 512 + lane * 8];
                ol[f] = __builtin_amdgcn_mfma_f32_16x16x32_bf16(ap, ones, ol[f], 0, 0, 0);
#pragma unroll
                for (int j2 = 0; j2 < 4; ++j2) {
                    short8 bv = *(const short8*)&Vs[(j2 * 16 + r16) * 128 + (((kk4 * 4 + quad) ^ (r16 & 7)) << 3)];
                    o[f][j2] = __builtin_amdgcn_mfma_f32_16x16x32_bf16(ap, bv, o[f][j2], 0, 0, 0);
                }
            }
        }
    }

    // epilogue: l in C-layout (lane already holds its 4 rows) — no shuffles
#pragma unroll
    for (int f = 0; f < 2; ++f) {
        float linv[4];
#pragma unroll
        for (int r = 0; r < 4; ++r)
            linv[r] = 1.0f / fmaxf(ol[f][r], 1.0e-30f);
        const int my_q = q0 + f * 64 + wave * 16 + quad * 4;
#pragma unroll
        for (int j2 = 0; j2 < 4; ++j2) {
            int d = j2 * 16 + r16;
#pragma unroll
            for (int r = 0; r < 4; ++r) {
                size_t oidx = ((size_t)(b * 1024 + my_q + r)) * 1024 + h * 64 + d;
                out[oidx] = o[f][j2][r] * linv[r];
            }
        }
    }
}

__global__ __launch_bounds__(256) void fill_sentinel_f(float* __restrict__ out,
                                                       float v, unsigned int n)
{
    unsigned int t = blockIdx.x * 256u + threadIdx.x;
    if (t < n) out[t] = v;
}

extern "C" void kernel_launch(void* const* d_in, const int* in_sizes, int n_in,
                              void* d_out, int out_size, void* d_ws, size_t ws_size,
                              hipStream_t stream) {
    bool sizes_ok = (n_in == 9) && in_sizes[0] == 4194304 && in_sizes[1] == 4096 &&
                    in_sizes[2] == 1048576 && in_sizes[3] == 1048576 && in_sizes[4] == 1024 &&
                    in_sizes[5] == 1048576 && in_sizes[6] == 1024 && in_sizes[7] == 1048576 &&
                    in_sizes[8] == 1024 && out_size == 4194304;
    if (!sizes_ok) {
        fill_sentinel_f<<<16384, 256, 0, stream>>>((float*)d_out, 100.0f, 4194304u);
        return;
    }
    if (ws_size < 50331652u) {
        fill_sentinel_f<<<16384, 256, 0, stream>>>((float*)d_out, 200.0f, 4194304u);
        return;
    }

    unsigned short* ws = (unsigned short*)d_ws;

    conv_in<<<3588, 256, 0, stream>>>(
        (const float*)d_in[0], (const float*)d_in[3], (const float*)d_in[5],
        (const float*)d_in[7], (const float*)d_in[4], (const float*)d_in[6],
        (const float*)d_in[8], (const float*)d_in[1], ws);

    const unsigned short* cseq = ws + 12582912u;
    const unsigned short* cwq  = ws + 16777216u;
    const unsigned short* cwk  = ws + 17825792u;
    const unsigned short* cwv  = ws + 18874368u;
    const unsigned short* cbq  = ws + 20971520u;
    const unsigned short* cbk  = ws + 20972544u;
    const unsigned short* cbv  = ws + 20973568u;
    const unsigned short* cpm  = ws + 20974592u;

    dim3 g1(32, 8, 3);
    qkv_proj<<<g1, 256, 0, stream>>>(cseq, cwq, cbq, cwk, cbk, cwv, cbv, ws);

    attn<<<512, 256, 0, stream>>>(ws, ws + 4194304u, ws + 8388608u, cpm, (float*)d_out);
}